// Round 6
// baseline (129.443 us; speedup 1.0000x reference)
//
#include <hip/hip_runtime.h>

// OESNN_SEPhIA_MultiTiled2: 32-step recurrent SNN, B=8192.
// R8 = R7 + register pinning. R7's VGPR_Count=72 (exactly the weight
// footprint) proved the recurring failure across R2/R3/R6/R7: the compiler
// sinks loop-invariant weight loads INTO the t-loop (remat-by-reload) and
// every iteration pays ~72 reloads + addr ops + vmcnt waits. Fix: after the
// preload, pass every weight through `asm volatile("" : "+v"(w))`. The
// opaque asm output cannot be rematerialized from the original load, so the
// values MUST stay VGPR-resident across the loop. Zero instructions emitted;
// numerics bit-identical to the PASSING R7 kernel (same ascending-w
// single-accumulator chains on split lanes, same shfl exchanges, same
// select-based LIF, same pon/poff precompute).
// Structure (verified R7): 16 lanes/elem, lane pair splits even/odd weight
// columns (72 weight regs/lane), partial sums exchanged via shfl_xor(1),
// 2048 waves = 2 waves/SIMD under __launch_bounds__(256,2).

namespace {
constexpr int Tn = 32;
constexpr int Bn = 8192;
constexpr int O_PW = 0;                       // spks0 (= pw0) [T,B,18]
constexpr int O_S1 = Tn * Bn * 18;            // spks1 [T,B,8]
constexpr int O_M0 = O_S1 + Tn * Bn * 8;      // mems0 [T,B,18]
constexpr int O_M1 = O_M0 + Tn * Bn * 18;     // mems1 [T,B,8]
}

__global__ __launch_bounds__(256, 2)
void oesnn_kernel(const float* __restrict__ x_in,
                  const float* __restrict__ W0g,   // [2,18,18]
                  const float* __restrict__ d0g,   // [2,9]
                  const float* __restrict__ W1g,   // [1,18,16]
                  const float* __restrict__ d1g,   // [1,8]
                  const float* __restrict__ peakg, // [36]
                  float* __restrict__ out)
{
    const int lt  = threadIdx.x & 63;         // lane in wave
    const int tid = blockIdx.x * 256 + threadIdx.x;
    const int b   = tid >> 4;                 // batch element (16 lanes/elem)
    const int h   = tid & 15;                 // lane within batch group
    const int sub = h >> 1;                   // R2's sub (0..7)
    const int par = h & 1;                    // 0: even cols, 1: odd cols
    const int tl  = sub >> 2;                 // layer-0 tile (0/1)
    const int q   = sub & 3;                  // lane-pair within tile
    const int j0  = (q == 0) ? 0 : (2 * q + 1);   // first in-tile channel
    const int nj  = (q == 0) ? 3 : 2;             // real channel count (pad to 3)

    // ---------------- per-lane weight preload into registers ----------------
    // ww[j][w] = W0[tl][w][2*jc + par] : this lane's half-column of chan j.
    // w1[w]    = W1[w][2*sub + par]    : this lane's half-column of output sub.
    float ww[3][18], w1[18];
    float dd0[3], pon[3], poff[3];
    #pragma unroll
    for (int j = 0; j < 3; ++j) {
        const int jc = (j < nj) ? (j0 + j) : j0;   // clamped dup stays in-pair
        dd0[j] = d0g[tl * 9 + jc];
        #pragma unroll
        for (int w = 0; w < 18; ++w)
            ww[j][w] = W0g[(tl * 18 + w) * 18 + 2 * jc + par];
        // pw0 takes exactly two values per channel: precompute via the
        // reference's complex-division -> abs -> square path (verbatim R2).
        const int c = tl * 9 + jc;
        const float wl    = 1550.0f + 0.8f * (float)c;
        const float halfw = 0.5f * (wl * 1e3f / 15000.0f);
        const float amp   = sqrtf((exp10f(peakg[c] / 10.0f) / 1000.0f) * 1e6f);
        {   // spike = 0: lo = (0.1 + 0i)/(1 + 0i) * amp
            const float lr = 0.1f * amp;
            const float a  = sqrtf(lr * lr);
            poff[j] = a * a;
        }
        {   // spike = 1: delta = -250 / (0.5*fwhm)
            const float delta = -250.0f / halfw;
            const float den = fmaf(delta, delta, 1.0f);
            const float qr  = fmaf(delta, delta, 0.1f) / den;     // (g + d^2)/den
            const float qi  = (delta - 0.1f * delta) / den;       // (d - g*d)/den
            const float lr = qr * amp, li = qi * amp;
            const float a  = sqrtf(fmaf(lr, lr, li * li));
            pon[j] = a * a;
        }
    }
    #pragma unroll
    for (int w = 0; w < 18; ++w)
        w1[w] = W1g[w * 16 + 2 * sub + par];
    const float dd1 = d1g[sub];

    // ---------------- PIN loop-invariants in VGPRs ----------------
    // Opaque no-op asm: the post-asm value cannot be rematerialized by
    // re-loading from global, so it must stay register-resident across the
    // t-loop. This is the fix for the VGPR_Count=72 reload pathology.
    #pragma unroll
    for (int j = 0; j < 3; ++j) {
        #pragma unroll
        for (int w = 0; w < 18; ++w) asm volatile("" : "+v"(ww[j][w]));
        asm volatile("" : "+v"(dd0[j]));
        asm volatile("" : "+v"(pon[j]));
        asm volatile("" : "+v"(poff[j]));
    }
    #pragma unroll
    for (int w = 0; w < 18; ++w) asm volatile("" : "+v"(w1[w]));

    // ---------------- state & pointers ----------------
    float mem0[3] = {0.f, 0.f, 0.f};   // identical on both pair lanes
    float mem1 = 0.f;

    const float* xp = x_in + (size_t)b * 36 + tl * 18;
    float* opw = out + O_PW + (size_t)b * 18 + tl * 9 + j0;   // even lane stores
    float* om0 = out + O_M0 + (size_t)b * 18 + tl * 9 + j0;   // odd lane stores
    float* os1 = out + O_S1 + (size_t)b * 8 + sub;            // even lane stores
    float* om1 = out + O_M1 + (size_t)b * 8 + sub;            // odd lane stores

    // prefetch t=0 inputs (18 floats = 9x float2, 8B-aligned)
    float2 xv[9];
    #pragma unroll
    for (int k = 0; k < 9; ++k) xv[k] = *(const float2*)(xp + 2 * k);

    const int base16 = lt & ~15;   // first lane of this element's 16-lane group

    #pragma unroll 1
    for (int t = 0; t < Tn; ++t) {
        // unpack current x, scale to optical power (reference: p_in = x * 1e-4)
        float p[18];
        #pragma unroll
        for (int k = 0; k < 9; ++k) {
            p[2 * k]     = xv[k].x * 1e-4f;
            p[2 * k + 1] = xv[k].y * 1e-4f;
        }
        // prefetch next timestep while computing this one
        xp += Bn * 36;
        if (t < Tn - 1) {
            #pragma unroll
            for (int k = 0; k < 9; ++k) xv[k] = *(const float2*)(xp + 2 * k);
        }

        // ---- layer 0: this lane's half-column dot, exchange, LIF, MRR ----
        float pwv[3];
        #pragma unroll
        for (int j = 0; j < 3; ++j) {
            float s = 0.f;
            #pragma unroll
            for (int w = 0; w < 18; ++w)
                s = fmaf(p[w], ww[j][w], s);      // ascending w, single acc
            const float o = __shfl_xor(s, 1, 64); // partner's half-sum
            const float se = par ? o : s;
            const float so = par ? s : o;
            const float c0 = (se - so) * dd0[j];  // identical on both lanes
            const float m  = mem0[j];
            const float m2 = (m > 0.55f) ? 0.0f : fmaf(0.95f, m, c0);
            mem0[j] = m2;
            pwv[j]  = (m2 > 0.55f) ? pon[j] : poff[j];
        }

        // store pw0 (even lane) / mem0 (odd lane); guard dup channel
        #pragma unroll
        for (int j = 0; j < 3; ++j) {
            if (j < nj) {
                if (par == 0) opw[j] = pwv[j];
                else          om0[j] = mem0[j];
            }
        }

        // ---- layer 1: gather 18 pw (from even lane of owner pair), dot ----
        float i1 = 0.f;
        #pragma unroll
        for (int c = 0; c < 18; ++c) {
            const int tlc = c / 9, jc2 = c % 9;
            const int qo  = (jc2 < 3) ? 0 : ((jc2 - 1) / 2);   // owner pair-in-tile
            const int st  = (qo == 0) ? 0 : (2 * qo + 1);
            const int r   = jc2 - st;                          // owner's reg index
            const float gp = __shfl(pwv[r], base16 + 2 * (tlc * 4 + qo), 64);
            i1 = fmaf(gp, w1[c], i1);             // ascending c, single acc
        }
        const float oi = __shfl_xor(i1, 1, 64);
        const float i1e = par ? oi : i1;
        const float i1o = par ? i1 : oi;
        const float c1 = (i1e - i1o) * dd1;       // identical on both lanes
        const float m  = mem1;
        const float m3 = (m > 0.25f) ? 0.0f : fmaf(0.95f, m, c1);
        mem1 = m3;
        if (par == 0) *os1 = (m3 > 0.25f) ? 1.0f : 0.0f;
        else          *om1 = m3;

        opw += Bn * 18;
        om0 += Bn * 18;
        os1 += Bn * 8;
        om1 += Bn * 8;
    }
}

extern "C" void kernel_launch(void* const* d_in, const int* in_sizes, int n_in,
                              void* d_out, int out_size, void* d_ws, size_t ws_size,
                              hipStream_t stream) {
    (void)in_sizes; (void)n_in; (void)out_size; (void)d_ws; (void)ws_size;
    const float* x  = (const float*)d_in[0];
    const float* W0 = (const float*)d_in[1];
    const float* d0 = (const float*)d_in[2];
    const float* W1 = (const float*)d_in[3];
    const float* d1 = (const float*)d_in[4];
    const float* pk = (const float*)d_in[5];
    float* out = (float*)d_out;

    dim3 grid(Bn * 16 / 256), block(256);   // 131072 threads = 2048 waves
    hipLaunchKernelGGL(oesnn_kernel, grid, block, 0, stream,
                       x, W0, d0, W1, d1, pk, out);
}